// Round 8
// baseline (76.920 us; speedup 1.0000x reference)
//
#include <hip/hip_runtime.h>

#define BATCH 64
#define NSAMP 1500
#define NFREQ 1251
#define NSEG  5
#define SEGLEN 300            // NSEG*SEGLEN == NSAMP, SEGLEN % 4 == 0
#define FBLK  256             // threads per block
#define FPT   5               // freqs per thread; FBLK*FPT = 1280 >= 1251

// ---------------------------------------------------------------------------
// Kernel 1: Goertzel partials, 5 freqs per thread.
// Grid (B, NSEG) = 320 blocks x 256 thr. Each thread runs FPT independent
// Goertzel recurrences over one 300-sample segment; one ds_read_b128 now
// feeds 4 samples x 5 freqs x 2 ops = 40 VALU instrs (LDS pipe was the
// round-7 bottleneck at 1 freq/thread: 12-cyc read per 16 VALU cyc).
// Same per-freq arithmetic as rounds 6-7 (bit-identical partials).
// Thread (0,0,0) zeroes d_out for kernel 2's atomicAdd (stream-ordered).
// ---------------------------------------------------------------------------
__global__ __launch_bounds__(256) void goertzel_kernel(
    const float* __restrict__ x,          // [B,N]
    const float* __restrict__ fs,         // [B]
    const float* __restrict__ sampling_f, // [1]
    const float* __restrict__ f_range,    // f_min first
    float2* __restrict__ pcs,             // [B,NSEG,NFREQ] partial (C,S)
    float* __restrict__ out)              // [1] zeroed here
{
    __shared__ float4 xs4[SEGLEN / 4];    // 75 float4
    const int b   = blockIdx.x;
    const int seg = blockIdx.y;
    const int tid = threadIdx.x;
    const int n0  = seg * SEGLEN;

    if (b == 0 && seg == 0 && tid == 0) out[0] = 0.0f;

    const float4* xg = reinterpret_cast<const float4*>(x + b * NSAMP + n0);
    for (int i = tid; i < SEGLEN / 4; i += FBLK) xs4[i] = xg[i];
    __syncthreads();

    // numpy arange fill semantics
    const float f_min = f_range[0];
    const float step  = sampling_f[0];
    const float delta = (f_min + step) - f_min;
    const float inv_fs = 1.0f / fs[b];

    float coef[FPT], s1[FPT], s2[FPT], rho[FPT];
#pragma unroll
    for (int j = 0; j < FPT; ++j) {
        const int fidx = j * FBLK + tid;
        const float fv = f_min + (float)fidx * delta;
        rho[j] = fv * inv_fs;                         // revolutions per sample
        float rf = rho[j] - floorf(rho[j]);
        coef[j] = 2.0f * __builtin_amdgcn_cosf(rf);
        s1[j] = 0.0f; s2[j] = 0.0f;
    }

    for (int k = 0; k < SEGLEN / 4; ++k) {
        float4 v = xs4[k];
#pragma unroll
        for (int j = 0; j < FPT; ++j) {
            float t;
            t = fmaf(coef[j], s1[j], v.x - s2[j]); s2[j] = s1[j]; s1[j] = t;
            t = fmaf(coef[j], s1[j], v.y - s2[j]); s2[j] = s1[j]; s1[j] = t;
            t = fmaf(coef[j], s1[j], v.z - s2[j]); s2[j] = s1[j]; s1[j] = t;
            t = fmaf(coef[j], s1[j], v.w - s2[j]); s2[j] = s1[j]; s1[j] = t;
        }
    }

    float2* row = pcs + (b * NSEG + seg) * NFREQ;
#pragma unroll
    for (int j = 0; j < FPT; ++j) {
        const int fidx = j * FBLK + tid;
        float aM  = (float)SEGLEN * rho[j];        aM  -= floorf(aM);
        float aM1 = (float)(SEGLEN - 1) * rho[j];  aM1 -= floorf(aM1);
        float a0  = (float)n0 * rho[j];            a0  -= floorf(a0);
        const float cM  = __builtin_amdgcn_cosf(aM);
        const float sM  = __builtin_amdgcn_sinf(aM);
        const float cM1 = __builtin_amdgcn_cosf(aM1);
        const float sM1 = __builtin_amdgcn_sinf(aM1);
        const float c0  = __builtin_amdgcn_cosf(a0);
        const float s0  = __builtin_amdgcn_sinf(a0);

        const float Cl = cM1 * s1[j] - cM * s2[j];
        const float Sl = sM1 * s1[j] - sM * s2[j];
        const float C  = c0 * Cl - s0 * Sl;
        const float S  = s0 * Cl + c0 * Sl;

        if (fidx < NFREQ) row[fidx] = make_float2(C, S);
    }
}

// ---------------------------------------------------------------------------
// Kernel 2 (unchanged from round 7): single-pass loss.
//  - closed-form np.argmin (monotone grid, +-2 window, identical fp32 expr)
//  - online softmax, shuffle-combined; owner thread stashes psd[idx]
//  - fused mean via atomicAdd into out (zeroed by kernel 1)
// ---------------------------------------------------------------------------
__global__ __launch_bounds__(256) void loss_kernel(
    const float2* __restrict__ pcs,       // [B,NSEG,NFREQ]
    const float* __restrict__ f_true,     // [B]
    const float* __restrict__ sampling_f,
    const float* __restrict__ f_range,
    float* __restrict__ out)              // [1]
{
    const int b    = blockIdx.x;
    const int tid  = threadIdx.x;
    const int wave = tid >> 6;
    const int lane = tid & 63;

    __shared__ float wm[4];
    __shared__ float wl[4];
    __shared__ float s_pidx;

    const float f_min = f_range[0];
    const float step  = sampling_f[0];
    const float delta = (f_min + step) - f_min;
    const float ft    = f_true[b];

    // closed-form argmin (np first-occurrence semantics)
    int iq = (int)((ft - f_min) / delta + 0.5f);
    int lo = iq - 2; if (lo < 0) lo = 0;
    int hi = iq + 2; if (hi > NFREQ - 1) hi = NFREQ - 1;
    int   idx   = lo;
    float bestd = fabsf((f_min + (float)lo * delta) - ft);
    for (int i = lo + 1; i <= hi; ++i) {
        float d = fabsf((f_min + (float)i * delta) - ft);
        if (d < bestd) { bestd = d; idx = i; }     // strict < : first occurrence
    }

    // one pass: assemble psd element, online max/sumexp
    float m = -INFINITY, l = 0.0f;
    for (int i = tid; i < NFREQ; i += 256) {
        float c = 0.0f, s = 0.0f;
#pragma unroll
        for (int g = 0; g < NSEG; ++g) {
            float2 v = pcs[(b * NSEG + g) * NFREQ + i];
            c += v.x; s += v.y;
        }
        float v = fmaf(c, c, s * s);
        if (i == idx) s_pidx = v;                  // exactly one thread
        float mn = fmaxf(m, v);
        l = l * __expf(m - mn) + __expf(v - mn);
        m = mn;
    }
    // wave combine (64 lanes)
    for (int off = 32; off > 0; off >>= 1) {
        float m2 = __shfl_down(m, off);
        float l2 = __shfl_down(l, off);
        float mn = fmaxf(m, m2);
        l = l * __expf(m - mn) + l2 * __expf(m2 - mn);
        m = mn;
    }
    if (lane == 0) { wm[wave] = m; wl[wave] = l; }
    __syncthreads();

    if (tid == 0) {
        float gm = wm[0], gl = wl[0];
#pragma unroll
        for (int w = 1; w < 4; ++w) {
            float mn = fmaxf(gm, wm[w]);
            gl = gl * __expf(gm - mn) + wl[w] * __expf(wm[w] - mn);
            gm = mn;
        }
        float sm  = __expf(s_pidx - gm) / gl;
        float per = -logf(sm + 1e-8f);
        atomicAdd(out, per * (1.0f / (float)BATCH));
    }
}

extern "C" void kernel_launch(void* const* d_in, const int* in_sizes, int n_in,
                              void* d_out, int out_size, void* d_ws, size_t ws_size,
                              hipStream_t stream) {
    const float* x          = (const float*)d_in[0];
    const float* f_true     = (const float*)d_in[1];
    const float* fs         = (const float*)d_in[2];
    // d_in[3] = deltas (unused)
    const float* sampling_f = (const float*)d_in[4];
    const float* f_range    = (const float*)d_in[5];

    float2* pcs = (float2*)d_ws;           // [B*NSEG*NFREQ] float2 = 3.2 MB

    dim3 g1(BATCH, NSEG);                  // 320 blocks x 4 waves
    goertzel_kernel<<<g1, FBLK, 0, stream>>>(x, fs, sampling_f, f_range, pcs,
                                             (float*)d_out);
    loss_kernel<<<BATCH, 256, 0, stream>>>(pcs, f_true, sampling_f, f_range,
                                           (float*)d_out);
}

// Round 9
// 74.762 us; speedup vs baseline: 1.0289x; 1.0289x over previous
//
#include <hip/hip_runtime.h>

#define BATCH 64
#define NSAMP 1500
#define NFREQ 1251
#define NSEG  5
#define SEGLEN 300            // NSEG*SEGLEN == NSAMP, SEGLEN % 4 == 0
#define FBLK  256             // freqs per block
#define FCHUNKS 5             // 5*256 = 1280 >= 1251

// ---------------------------------------------------------------------------
// Kernel 1 (round-7 config — measured best, 75.6 us total): Goertzel partials.
// Grid (B, FCHUNKS, NSEG) = 1600 blocks x 4 waves -> 25 waves/CU.
// Occupancy dominates here: 320-block variants (r5, r8) both regressed.
//   s_k = x_k + 2cos(w) s_{k-1} - s_{k-2}
//   C_loc = cos((M-1)w) s1 - cos(Mw) s2 ; S_loc = sin((M-1)w) s1 - sin(Mw) s2
// rotated by segment-start phase. Trig in REVOLUTIONS (v_sin/v_cos).
// Thread (0,0,0) zeroes d_out for kernel 2's atomicAdd (stream-ordered).
// ---------------------------------------------------------------------------
__global__ __launch_bounds__(256) void goertzel_kernel(
    const float* __restrict__ x,          // [B,N]
    const float* __restrict__ fs,         // [B]
    const float* __restrict__ sampling_f, // [1]
    const float* __restrict__ f_range,    // f_min first
    float2* __restrict__ pcs,             // [B,NSEG,NFREQ] partial (C,S)
    float* __restrict__ out)              // [1] zeroed here
{
    __shared__ float4 xs4[SEGLEN / 4];    // 75 float4
    const int b   = blockIdx.x;
    const int seg = blockIdx.z;
    const int tid = threadIdx.x;
    const int n0  = seg * SEGLEN;

    if (b == 0 && seg == 0 && blockIdx.y == 0 && tid == 0) out[0] = 0.0f;

    const float4* xg = reinterpret_cast<const float4*>(x + b * NSAMP + n0);
    for (int i = tid; i < SEGLEN / 4; i += FBLK) xs4[i] = xg[i];
    __syncthreads();

    const int fidx = blockIdx.y * FBLK + tid;
    if (fidx >= NFREQ) return;

    // numpy arange fill semantics
    const float f_min = f_range[0];
    const float step  = sampling_f[0];
    const float delta = (f_min + step) - f_min;
    const float fv    = f_min + (float)fidx * delta;

    const float rho = fv / fs[b];                 // revolutions per sample
    float rf = rho - floorf(rho);
    const float coef = 2.0f * __builtin_amdgcn_cosf(rf);

    float s1 = 0.0f, s2 = 0.0f;
#pragma unroll 5
    for (int k = 0; k < SEGLEN / 4; ++k) {
        float4 v = xs4[k];
        float t;
        t = fmaf(coef, s1, v.x - s2); s2 = s1; s1 = t;
        t = fmaf(coef, s1, v.y - s2); s2 = s1; s1 = t;
        t = fmaf(coef, s1, v.z - s2); s2 = s1; s1 = t;
        t = fmaf(coef, s1, v.w - s2); s2 = s1; s1 = t;
    }

    float aM  = (float)SEGLEN * rho;        aM  -= floorf(aM);
    float aM1 = (float)(SEGLEN - 1) * rho;  aM1 -= floorf(aM1);
    float a0  = (float)n0 * rho;            a0  -= floorf(a0);
    const float cM  = __builtin_amdgcn_cosf(aM);
    const float sM  = __builtin_amdgcn_sinf(aM);
    const float cM1 = __builtin_amdgcn_cosf(aM1);
    const float sM1 = __builtin_amdgcn_sinf(aM1);
    const float c0  = __builtin_amdgcn_cosf(a0);
    const float s0  = __builtin_amdgcn_sinf(a0);

    const float Cl = cM1 * s1 - cM * s2;
    const float Sl = sM1 * s1 - sM * s2;
    const float C  = c0 * Cl - s0 * Sl;
    const float S  = s0 * Cl + c0 * Sl;

    pcs[(b * NSEG + seg) * NFREQ + fidx] = make_float2(C, S);
}

// ---------------------------------------------------------------------------
// Kernel 2 (round-7, unchanged): single-pass loss.
//  - closed-form np.argmin (monotone grid, +-2 window, identical fp32 expr)
//  - online softmax, shuffle-combined; owner thread stashes psd[idx]
//  - fused mean via atomicAdd into out (zeroed by kernel 1)
// ---------------------------------------------------------------------------
__global__ __launch_bounds__(256) void loss_kernel(
    const float2* __restrict__ pcs,       // [B,NSEG,NFREQ]
    const float* __restrict__ f_true,     // [B]
    const float* __restrict__ sampling_f,
    const float* __restrict__ f_range,
    float* __restrict__ out)              // [1]
{
    const int b    = blockIdx.x;
    const int tid  = threadIdx.x;
    const int wave = tid >> 6;
    const int lane = tid & 63;

    __shared__ float wm[4];
    __shared__ float wl[4];
    __shared__ float s_pidx;

    const float f_min = f_range[0];
    const float step  = sampling_f[0];
    const float delta = (f_min + step) - f_min;
    const float ft    = f_true[b];

    // closed-form argmin (np first-occurrence semantics)
    int iq = (int)((ft - f_min) / delta + 0.5f);
    int lo = iq - 2; if (lo < 0) lo = 0;
    int hi = iq + 2; if (hi > NFREQ - 1) hi = NFREQ - 1;
    int   idx   = lo;
    float bestd = fabsf((f_min + (float)lo * delta) - ft);
    for (int i = lo + 1; i <= hi; ++i) {
        float d = fabsf((f_min + (float)i * delta) - ft);
        if (d < bestd) { bestd = d; idx = i; }     // strict < : first occurrence
    }

    // one pass: assemble psd element, online max/sumexp
    float m = -INFINITY, l = 0.0f;
    for (int i = tid; i < NFREQ; i += 256) {
        float c = 0.0f, s = 0.0f;
#pragma unroll
        for (int g = 0; g < NSEG; ++g) {
            float2 v = pcs[(b * NSEG + g) * NFREQ + i];
            c += v.x; s += v.y;
        }
        float v = fmaf(c, c, s * s);
        if (i == idx) s_pidx = v;                  // exactly one thread
        float mn = fmaxf(m, v);
        l = l * __expf(m - mn) + __expf(v - mn);
        m = mn;
    }
    // wave combine (64 lanes)
    for (int off = 32; off > 0; off >>= 1) {
        float m2 = __shfl_down(m, off);
        float l2 = __shfl_down(l, off);
        float mn = fmaxf(m, m2);
        l = l * __expf(m - mn) + l2 * __expf(m2 - mn);
        m = mn;
    }
    if (lane == 0) { wm[wave] = m; wl[wave] = l; }
    __syncthreads();

    if (tid == 0) {
        float gm = wm[0], gl = wl[0];
#pragma unroll
        for (int w = 1; w < 4; ++w) {
            float mn = fmaxf(gm, wm[w]);
            gl = gl * __expf(gm - mn) + wl[w] * __expf(wm[w] - mn);
            gm = mn;
        }
        float sm  = __expf(s_pidx - gm) / gl;
        float per = -logf(sm + 1e-8f);
        atomicAdd(out, per * (1.0f / (float)BATCH));
    }
}

extern "C" void kernel_launch(void* const* d_in, const int* in_sizes, int n_in,
                              void* d_out, int out_size, void* d_ws, size_t ws_size,
                              hipStream_t stream) {
    const float* x          = (const float*)d_in[0];
    const float* f_true     = (const float*)d_in[1];
    const float* fs         = (const float*)d_in[2];
    // d_in[3] = deltas (unused)
    const float* sampling_f = (const float*)d_in[4];
    const float* f_range    = (const float*)d_in[5];

    float2* pcs = (float2*)d_ws;           // [B*NSEG*NFREQ] float2 = 3.2 MB

    dim3 g1(BATCH, FCHUNKS, NSEG);         // 64 x 5 x 5 = 1600 blocks x 4 waves
    goertzel_kernel<<<g1, FBLK, 0, stream>>>(x, fs, sampling_f, f_range, pcs,
                                             (float*)d_out);
    loss_kernel<<<BATCH, 256, 0, stream>>>(pcs, f_true, sampling_f, f_range,
                                           (float*)d_out);
}